// Round 1
// 597.532 us; speedup vs baseline: 1.0446x; 1.0446x over previous
//
#include <hip/hip_runtime.h>
#include <math.h>

#define BB 8
#define SS 512
#define VV 32000
#define ROWS (BB * SS)        // 4096
#define CHUNKS 4
#define CF4 2000              // float4s per chunk (row = 8000 float4s / 4 chunks)

typedef float f4 __attribute__((ext_vector_type(4)));

// Kernel 1: one block per (row, chunk). Invalid rows (s >= word_len[b]) exit
// before touching predict. Streaming loads use the nontemporal (evict-first)
// policy: predict is read exactly once, so caching its 262 MB of live lines
// in L2/L3 only evicts data the finalize gather could hit.
__global__ __launch_bounds__(256) void chunk_sumexp_kernel(
    const float* __restrict__ predict,
    const int*   __restrict__ mask,
    float*       __restrict__ ws)
{
    const int bid   = blockIdx.x;
    const int row   = bid >> 2;
    const int chunk = bid & 3;
    const int b     = row >> 9;
    const int s     = row & 511;
    if (s >= mask[b]) return;

    const f4* rp4 = (const f4*)(predict + (size_t)row * VV) + (size_t)chunk * CF4;
    const int tid = threadIdx.x;

    // 8 loads in flight before any exp work (7 unconditional + 1 predicated;
    // 2000 = 7*256 + 208) -> max memory-level parallelism.
    f4 v0 = __builtin_nontemporal_load(rp4 + tid);
    f4 v1 = __builtin_nontemporal_load(rp4 + tid + 256);
    f4 v2 = __builtin_nontemporal_load(rp4 + tid + 512);
    f4 v3 = __builtin_nontemporal_load(rp4 + tid + 768);
    f4 v4 = __builtin_nontemporal_load(rp4 + tid + 1024);
    f4 v5 = __builtin_nontemporal_load(rp4 + tid + 1280);
    f4 v6 = __builtin_nontemporal_load(rp4 + tid + 1536);
    float s7 = 0.0f;
    if (tid < CF4 - 7 * 256) {          // tid < 208
        f4 v7 = __builtin_nontemporal_load(rp4 + tid + 1792);
        s7 = __expf(v7.x) + __expf(v7.y) + __expf(v7.z) + __expf(v7.w);
    }

    float sum = s7
        + __expf(v0.x) + __expf(v0.y) + __expf(v0.z) + __expf(v0.w)
        + __expf(v1.x) + __expf(v1.y) + __expf(v1.z) + __expf(v1.w)
        + __expf(v2.x) + __expf(v2.y) + __expf(v2.z) + __expf(v2.w)
        + __expf(v3.x) + __expf(v3.y) + __expf(v3.z) + __expf(v3.w)
        + __expf(v4.x) + __expf(v4.y) + __expf(v4.z) + __expf(v4.w)
        + __expf(v5.x) + __expf(v5.y) + __expf(v5.z) + __expf(v5.w)
        + __expf(v6.x) + __expf(v6.y) + __expf(v6.z) + __expf(v6.w);

    // wave(64) shuffle reduction
    #pragma unroll
    for (int off = 32; off > 0; off >>= 1)
        sum += __shfl_down(sum, off, 64);

    // cross-wave reduction (4 waves)
    __shared__ float ssum[4];
    if ((tid & 63) == 0) ssum[tid >> 6] = sum;
    __syncthreads();
    if (tid == 0)
        ws[bid] = ssum[0] + ssum[1] + ssum[2] + ssum[3];
}

// Kernel 2: single block. Restructured for memory-level parallelism: all 16
// ws reads + 16 target reads issue first, then all 16 predict gathers issue
// unconditionally (indices are always in-bounds, even for masked-out rows),
// then the arithmetic. ~2 HBM latency waves instead of 16 dependent
// mask->target->predict chains.
__global__ __launch_bounds__(256) void finalize_kernel(
    const float* __restrict__ predict,
    const int*   __restrict__ target,
    const int*   __restrict__ mask,
    const float* __restrict__ ws,
    float*       __restrict__ out)
{
    const int tid = threadIdx.x;

    __shared__ int wls[BB];
    if (tid < BB) wls[tid] = mask[tid];
    __syncthreads();

    float4 w4[ROWS / 256];
    int    tg[ROWS / 256];
    float  xt[ROWS / 256];

    #pragma unroll
    for (int k = 0; k < ROWS / 256; ++k) {   // 16 rows per thread, coalesced
        const int r = tid + k * 256;
        tg[k] = target[r];                   // always valid memory
        w4[k] = ((const float4*)ws)[r];      // garbage for invalid rows; discarded
    }

    #pragma unroll
    for (int k = 0; k < ROWS / 256; ++k) {
        const int r = tid + k * 256;
        xt[k] = predict[(size_t)r * VV + tg[k]];   // always in-bounds
    }

    float acc = 0.0f;
    #pragma unroll
    for (int k = 0; k < ROWS / 256; ++k) {
        const int r  = tid + k * 256;
        const int s  = r & 511;
        const int wl = wls[r >> 9];
        if (s < wl) {
            const float4 p = w4[k];
            const float  S = (p.x + p.y) + (p.z + p.w);
            acc += (__logf(S) - xt[k]) / ((float)wl * (float)BB);
        }
    }

    #pragma unroll
    for (int off = 32; off > 0; off >>= 1)
        acc += __shfl_down(acc, off, 64);

    __shared__ float ssum[4];
    if ((tid & 63) == 0) ssum[tid >> 6] = acc;
    __syncthreads();
    if (tid == 0)
        out[0] = ssum[0] + ssum[1] + ssum[2] + ssum[3];
}

extern "C" void kernel_launch(void* const* d_in, const int* in_sizes, int n_in,
                              void* d_out, int out_size, void* d_ws, size_t ws_size,
                              hipStream_t stream) {
    const float* predict = (const float*)d_in[0];
    const int*   target  = (const int*)  d_in[1];
    const int*   mask    = (const int*)  d_in[2];
    float* out = (float*)d_out;
    float* ws  = (float*)d_ws;

    chunk_sumexp_kernel<<<ROWS * CHUNKS, 256, 0, stream>>>(predict, mask, ws);
    finalize_kernel<<<1, 256, 0, stream>>>(predict, target, mask, ws, out);
}